// Round 12
// baseline (3472.570 us; speedup 1.0000x reference)
//
#include <hip/hip_runtime.h>
#include <math.h>

// ---- Problem constants ----
constexpr int BATCH  = 256;
constexpr int SEQ    = 77;
constexpr int DMODEL = 512;
constexpr int NHEAD  = 8;
constexpr int DHEAD  = 64;
constexpr int DFF    = 2048;
constexpr int NLAYER = 12;
constexpr int NTOK   = BATCH * SEQ;      // 19712 = 77*256
constexpr int NQKV   = 3 * DMODEL;       // 1536
constexpr float NEGBIG = -3.402823466e38f;

typedef __attribute__((ext_vector_type(8))) short bf16x8;
typedef __attribute__((ext_vector_type(4))) float f32x4;
typedef __attribute__((ext_vector_type(8))) unsigned short u16x8;

typedef __attribute__((address_space(3))) unsigned char lds_u8;
typedef const __attribute__((address_space(1))) unsigned char g_u8;

__device__ __forceinline__ unsigned short f2bf(float f) {
    unsigned u = __float_as_uint(f);
    u = (u + 0x7FFF + ((u >> 16) & 1)) >> 16;
    return (unsigned short)u;
}

#define VMCNT4 asm volatile("s_waitcnt vmcnt(4)" ::: "memory")
#define LGKM0  asm volatile("s_waitcnt lgkmcnt(0)" ::: "memory")
#define SCHEDB __builtin_amdgcn_sched_barrier(0)
#define BARRIER do { SCHEDB; __builtin_amdgcn_s_barrier(); SCHEDB; } while (0)

// ======================================================================
// Weight conversion (runs every launch; deterministic).
// ======================================================================
__global__ __launch_bounds__(256) void conv_qkv_kernel(
    const float* __restrict__ qw, const float* __restrict__ kw,
    const float* __restrict__ vw, unsigned short* __restrict__ dst)
{
    int i4 = blockIdx.x * 256 + threadIdx.x;
    int e = i4 * 4;
    int l = e / (NQKV * DMODEL);
    int rem = e - l * (NQKV * DMODEL);
    int row = rem >> 9;
    int k   = rem & 511;
    const float* src;
    float scale = 1.0f;
    size_t lbase = (size_t)l * DMODEL * DMODEL;
    if (row < 512)       { src = qw + lbase + (size_t)row * DMODEL + k; scale = 0.125f; }
    else if (row < 1024) { src = kw + lbase + (size_t)(row - 512) * DMODEL + k; }
    else                 { src = vw + lbase + (size_t)(row - 1024) * DMODEL + k; }
    float4 v = *(const float4*)src;
    ushort4 o;
    o.x = f2bf(v.x * scale); o.y = f2bf(v.y * scale);
    o.z = f2bf(v.z * scale); o.w = f2bf(v.w * scale);
    *(ushort4*)&dst[e] = o;
}

__global__ __launch_bounds__(256) void conv_kernel(
    const float* __restrict__ src, unsigned short* __restrict__ dst)
{
    int e = (blockIdx.x * 256 + threadIdx.x) * 4;
    float4 v = *(const float4*)&src[e];
    ushort4 o;
    o.x = f2bf(v.x); o.y = f2bf(v.y); o.z = f2bf(v.z); o.w = f2bf(v.w);
    *(ushort4*)&dst[e] = o;
}

__global__ __launch_bounds__(256) void bias_qkv_kernel(
    const float* __restrict__ qb, const float* __restrict__ kb,
    const float* __restrict__ vb, float* __restrict__ dst)
{
    int e = blockIdx.x * 256 + threadIdx.x;
    int l = e / NQKV;
    int row = e - l * NQKV;
    float v;
    if (row < 512)       v = qb[l * DMODEL + row] * 0.125f;
    else if (row < 1024) v = kb[l * DMODEL + row - 512];
    else                 v = vb[l * DMODEL + row - 1024];
    dst[e] = v;
}

// ======================================================================
// Embedding
// ======================================================================
__global__ __launch_bounds__(256) void embed_kernel(
    const int* __restrict__ ids, const float* __restrict__ tok,
    const float* __restrict__ pos, float* __restrict__ x)
{
    int f = blockIdx.x * 256 + threadIdx.x;
    int total = NTOK * (DMODEL / 4);
    if (f >= total) return;
    int n  = f >> 7;
    int d4 = f & 127;
    int s  = n % SEQ;
    int id = ids[n];
    float4 t = *(const float4*)&tok[(size_t)id * DMODEL + d4 * 4];
    float4 p = *(const float4*)&pos[(size_t)s  * DMODEL + d4 * 4];
    float4 o; o.x = t.x + p.x; o.y = t.y + p.y; o.z = t.z + p.z; o.w = t.w + p.w;
    *(float4*)&x[(size_t)n * DMODEL + d4 * 4] = o;
}

// ======================================================================
// LayerNorm: one wave per row of 512.
// ======================================================================
template <bool BF16OUT>
__global__ __launch_bounds__(256) void ln_kernel(
    const float* __restrict__ x, const float* __restrict__ w,
    const float* __restrict__ b, void* __restrict__ out, int nrows)
{
    int row = blockIdx.x * 4 + (threadIdx.x >> 6);
    if (row >= nrows) return;
    int ln = threadIdx.x & 63;
    const float* xr = x + (size_t)row * DMODEL + ln * 8;
    float4 v0 = *(const float4*)xr;
    float4 v1 = *(const float4*)(xr + 4);
    float va[8] = {v0.x, v0.y, v0.z, v0.w, v1.x, v1.y, v1.z, v1.w};
    float sum = 0.f, sq = 0.f;
#pragma unroll
    for (int j = 0; j < 8; ++j) { sum += va[j]; sq = fmaf(va[j], va[j], sq); }
#pragma unroll
    for (int o = 32; o; o >>= 1) { sum += __shfl_xor(sum, o); sq += __shfl_xor(sq, o); }
    float mu  = sum * (1.0f / DMODEL);
    float var = sq * (1.0f / DMODEL) - mu * mu;
    var = fmaxf(var, 0.0f);
    float inv = 1.0f / sqrtf(var + 1e-5f);
    const float* wp = w + ln * 8;
    const float* bp = b + ln * 8;
    float o8[8];
#pragma unroll
    for (int j = 0; j < 8; ++j) o8[j] = (va[j] - mu) * inv * wp[j] + bp[j];
    if (BF16OUT) {
        u16x8 pk;
#pragma unroll
        for (int j = 0; j < 8; ++j) pk[j] = f2bf(o8[j]);
        *(u16x8*)((unsigned short*)out + (size_t)row * DMODEL + ln * 8) = pk;
    } else {
        float* op = (float*)out + (size_t)row * DMODEL + ln * 8;
        *(float4*)op       = make_float4(o8[0], o8[1], o8[2], o8[3]);
        *(float4*)(op + 4) = make_float4(o8[4], o8[5], o8[6], o8[7]);
    }
}

// ======================================================================
// 8-phase bf16 MFMA GEMM: 256x256 tile, BK=64, 512 thr (8 waves 2Mx4N).
// Counted vmcnt(4) at P4/P8. Padded LDS epilogue. MODE 0/2/3.
// ======================================================================
template <int MODE, bool OUTBF>
__global__ __launch_bounds__(512, 2) void gemm8_bf16(
    const unsigned short* __restrict__ A, const unsigned short* __restrict__ W,
    const float* __restrict__ bias, const float* __restrict__ R,
    void* __restrict__ Cout, int M, int N, int K, int gx)
{
    __shared__ __align__(16) char lds[135168];
    const int nwg = gridDim.x;
    const int wg  = blockIdx.x;
    const int q8  = nwg >> 3, r8 = nwg & 7;
    const int xcd = wg & 7, pos = wg >> 3;
    const int start = (xcd < r8) ? xcd * (q8 + 1) : r8 * (q8 + 1) + (xcd - r8) * q8;
    const int newid = start + pos;
    const int by = newid / gx;
    const int bx = newid - by * gx;
    const int m0 = by * 256;
    const int n0 = bx * 256;

    const int tid  = threadIdx.x;
    const int wid  = tid >> 6;
    const int lane = tid & 63;
    const int wr   = wid >> 2;
    const int wc   = wid & 3;
    const int lhi  = lane >> 4;
    const int llo  = lane & 15;

    const int srow  = tid >> 3;
    const int cglob = (tid & 7) ^ (srow & 7);
    const unsigned short* Ap = A + (size_t)(m0 + srow) * K + cglob * 8;
    const unsigned short* Wp = W + (size_t)(n0 + srow) * K + cglob * 8;
    const int NT  = K >> 6;
    const int NT2 = K >> 7;

    const int cb0 = ((0 * 4 + lhi) ^ (llo & 7)) * 16;
    const int cb1 = ((1 * 4 + lhi) ^ (llo & 7)) * 16;
    const int rbA0 = (wr * 128 + 0 * 64 + llo) * 128;
    const int rbA1 = (wr * 128 + 1 * 64 + llo) * 128;
    const int rbB0 = (wc * 64 + 0 * 32 + llo) * 128;
    const int rbB1 = (wc * 64 + 1 * 32 + llo) * 128;

    f32x4 acc[8][4];
#pragma unroll
    for (int i = 0; i < 8; ++i)
#pragma unroll
        for (int j = 0; j < 4; ++j) acc[i][j] = (f32x4){0.f, 0.f, 0.f, 0.f};

    bf16x8 am[4][2], bn0[2][2], bn1[2][2];

    auto stA = [&](int b, int h, int kt) {
#pragma unroll
        for (int i = h * 2; i < h * 2 + 2; ++i)
            __builtin_amdgcn_global_load_lds(
                (g_u8*)(Ap + (size_t)i * 64 * K + kt * 64),
                (lds_u8*)(lds + b * 32768 + i * 8192 + wid * 1024), 16, 0, 0);
    };
    auto stB = [&](int b, int h, int kt) {
#pragma unroll
        for (int i = h * 2; i < h * 2 + 2; ++i)
            __builtin_amdgcn_global_load_lds(
                (g_u8*)(Wp + (size_t)i * 64 * K + kt * 64),
                (lds_u8*)(lds + 65536 + b * 32768 + i * 8192 + wid * 1024), 16, 0, 0);
    };
    auto rdA = [&](int b, int mh) {
        int base = b * 32768 + (mh ? rbA1 : rbA0);
#pragma unroll
        for (int fm = 0; fm < 4; ++fm) {
            am[fm][0] = *(const bf16x8*)(lds + base + fm * 2048 + cb0);
            am[fm][1] = *(const bf16x8*)(lds + base + fm * 2048 + cb1);
        }
    };
    auto rdB = [&](int b, int nh, bf16x8 (&bn)[2][2]) {
        int base = 65536 + b * 32768 + (nh ? rbB1 : rbB0);
#pragma unroll
        for (int fn = 0; fn < 2; ++fn) {
            bn[fn][0] = *(const bf16x8*)(lds + base + fn * 2048 + cb0);
            bn[fn][1] = *(const bf16x8*)(lds + base + fn * 2048 + cb1);
        }
    };
    auto mq = [&](int mh, int nh, bf16x8 (&bn)[2][2]) {
        __builtin_amdgcn_s_setprio(1);
#pragma unroll
        for (int fm = 0; fm < 4; ++fm)
#pragma unroll
            for (int fn = 0; fn < 2; ++fn)
#pragma unroll
                for (int ks = 0; ks < 2; ++ks)
                    acc[mh * 4 + fm][nh * 2 + fn] =
                        __builtin_amdgcn_mfma_f32_16x16x32_bf16(
                            am[fm][ks], bn[fn][ks], acc[mh * 4 + fm][nh * 2 + fn], 0, 0, 0);
        __builtin_amdgcn_s_setprio(0);
    };

    stA(0, 0, 0); stA(0, 1, 0);
    stB(0, 0, 0); stB(0, 1, 0);
    stB(1, 0, 1); stB(1, 1, 1);
    VMCNT4;
    BARRIER;

    for (int it = 0; it < NT2; ++it) {
        const int k1 = 2 * it + 1;
        const int k2 = (2 * it + 2 < NT) ? 2 * it + 2 : NT - 1;
        const int k3 = (2 * it + 3 < NT) ? 2 * it + 3 : NT - 1;
        rdA(0, 0); rdB(0, 0, bn0);
        stA(1, 0, k1);
        LGKM0; BARRIER;
        mq(0, 0, bn0);
        rdB(0, 1, bn1);
        stA(1, 1, k1);
        LGKM0; BARRIER;
        mq(0, 1, bn1);
        rdA(0, 1);
        stB(0, 0, k2);
        LGKM0; BARRIER;
        mq(1, 1, bn1);
        stB(0, 1, k2);
        VMCNT4; BARRIER;
        mq(1, 0, bn0);
        rdA(1, 0); rdB(1, 0, bn0);
        stA(0, 0, k2);
        LGKM0; BARRIER;
        mq(0, 0, bn0);
        rdB(1, 1, bn1);
        stA(0, 1, k2);
        LGKM0; BARRIER;
        mq(0, 1, bn1);
        rdA(1, 1);
        stB(1, 0, k3);
        LGKM0; BARRIER;
        mq(1, 1, bn1);
        stB(1, 1, k3);
        VMCNT4; BARRIER;
        mq(1, 0, bn0);
    }

    if (OUTBF) {
        unsigned short* sb = (unsigned short*)lds;   // [256][264]
#pragma unroll
        for (int j = 0; j < 4; ++j) {
            int colL = wc * 64 + j * 16 + llo;
            float bv = bias[n0 + colL];
#pragma unroll
            for (int i = 0; i < 8; ++i) {
                int rowL = wr * 128 + i * 16 + lhi * 4;
#pragma unroll
                for (int r = 0; r < 4; ++r) {
                    float o = acc[i][j][r] + bv;
                    if (MODE == 2) o = o / (1.0f + __expf(-1.702f * o));
                    sb[(rowL + r) * 264 + colL] = f2bf(o);
                }
            }
        }
        __syncthreads();
        const int l5 = lane & 31, lh2 = lane >> 5;
#pragma unroll
        for (int rr = 0; rr < 16; ++rr) {
            int rowL = rr * 16 + wid * 2 + lh2;
            u16x8 v = *(const u16x8*)&sb[rowL * 264 + l5 * 8];
            *(u16x8*)((unsigned short*)Cout + (size_t)(m0 + rowL) * N + n0 + l5 * 8) = v;
        }
    } else {
        float* sf = (float*)lds;                     // [128][260]
#pragma unroll
        for (int mh = 0; mh < 2; ++mh) {
            if (mh) __syncthreads();
            if (wr == mh) {
#pragma unroll
                for (int j = 0; j < 4; ++j) {
                    int colL = wc * 64 + j * 16 + llo;
                    float bv = bias[n0 + colL];
#pragma unroll
                    for (int i = 0; i < 8; ++i) {
                        int rowL = i * 16 + lhi * 4;
#pragma unroll
                        for (int r = 0; r < 4; ++r)
                            sf[(rowL + r) * 260 + colL] = acc[i][j][r] + bv;
                    }
                }
            }
            __syncthreads();
#pragma unroll
            for (int rr = 0; rr < 16; ++rr) {
                int rowL = rr * 8 + wid;
                size_t gidx = (size_t)(m0 + mh * 128 + rowL) * N + n0 + lane * 4;
                f32x4 v = *(const f32x4*)&sf[rowL * 260 + lane * 4];
                if (MODE == 3) {
                    f32x4 rv = *(const f32x4*)&R[gidx];
                    v = v + rv;
                }
                *(f32x4*)((float*)Cout + gidx) = v;
            }
        }
    }
}

// ======================================================================
// Half-M variant: 128x256 tile, BK=64, 512 thr (8 waves; per-wave 64x64).
// Same 8-phase skeleton; vmcnt FIFO re-derived: prologue issues 10 instrs,
// buf0 = oldest 6 -> vmcnt(4); P4/P8 identical. For N=512 GEMMs the grid
// becomes 308 blocks (was 154 = 40% idle CUs). LDS 96 KB.
// ======================================================================
template <int MODE, bool OUTBF>
__global__ __launch_bounds__(512, 2) void gemm8h_bf16(
    const unsigned short* __restrict__ A, const unsigned short* __restrict__ W,
    const float* __restrict__ bias, const float* __restrict__ R,
    void* __restrict__ Cout, int M, int N, int K, int gx)
{
    __shared__ __align__(16) char lds[98304];  // A:[0,32K) 2buf; B:[32K,96K) 2buf
    const int nwg = gridDim.x;
    const int wg  = blockIdx.x;
    const int q8  = nwg >> 3, r8 = nwg & 7;
    const int xcd = wg & 7, pos = wg >> 3;
    const int start = (xcd < r8) ? xcd * (q8 + 1) : r8 * (q8 + 1) + (xcd - r8) * q8;
    const int newid = start + pos;
    const int by = newid / gx;
    const int bx = newid - by * gx;
    const int m0 = by * 128;
    const int n0 = bx * 256;

    const int tid  = threadIdx.x;
    const int wid  = tid >> 6;
    const int lane = tid & 63;
    const int wr   = wid >> 2;          // 0..1 (64 m-rows each)
    const int wc   = wid & 3;           // 0..3 (64 n-cols each)
    const int lhi  = lane >> 4;
    const int llo  = lane & 15;

    const int srow  = tid >> 3;
    const int cglob = (tid & 7) ^ (srow & 7);
    const unsigned short* Ap = A + (size_t)(m0 + srow) * K + cglob * 8;
    const unsigned short* Wp = W + (size_t)(n0 + srow) * K + cglob * 8;
    const int NT  = K >> 6;
    const int NT2 = K >> 7;

    const int cb0 = ((0 * 4 + lhi) ^ (llo & 7)) * 16;
    const int cb1 = ((1 * 4 + lhi) ^ (llo & 7)) * 16;

    f32x4 acc[4][4];
#pragma unroll
    for (int i = 0; i < 4; ++i)
#pragma unroll
        for (int j = 0; j < 4; ++j) acc[i][j] = (f32x4){0.f, 0.f, 0.f, 0.f};

    bf16x8 am[2][2], bn0[2][2], bn1[2][2];

    // A: 1 instr per (buf, half): rows h*64+srow -> lds b*16384 + h*8192 + t*16
    auto stA = [&](int b, int h, int kt) {
        __builtin_amdgcn_global_load_lds(
            (g_u8*)(Ap + (size_t)h * 64 * K + kt * 64),
            (lds_u8*)(lds + b * 16384 + h * 8192 + wid * 1024), 16, 0, 0);
    };
    // B: 2 instrs per (buf, half): rows i*64+srow
    auto stB = [&](int b, int h, int kt) {
#pragma unroll
        for (int i = h * 2; i < h * 2 + 2; ++i)
            __builtin_amdgcn_global_load_lds(
                (g_u8*)(Wp + (size_t)i * 64 * K + kt * 64),
                (lds_u8*)(lds + 32768 + b * 32768 + i * 8192 + wid * 1024), 16, 0, 0);
    };
    auto rdA = [&](int b, int mh) {
        int base = b * 16384 + (wr * 64 + mh * 32 + llo) * 128;
#pragma unroll
        for (int fm = 0; fm < 2; ++fm) {
            am[fm][0] = *(const bf16x8*)(lds + base + fm * 2048 + cb0);
            am[fm][1] = *(const bf16x8*)(lds + base + fm * 2048 + cb1);
        }
    };
    auto rdB = [&](int b, int nh, bf16x8 (&bn)[2][2]) {
        int base = 32768 + b * 32768 + (wc * 64 + nh * 32 + llo) * 128;
#pragma unroll
        for (int fn = 0; fn < 2; ++fn) {
            bn[fn][0] = *(const bf16x8*)(lds + base + fn * 2048 + cb0);
            bn[fn][1] = *(const bf16x8*)(lds + base + fn * 2048 + cb1);
        }
    };
    auto mq = [&](int mh, int nh, bf16x8 (&bn)[2][2]) {
        __builtin_amdgcn_s_setprio(1);
#pragma unroll
        for (int fm = 0; fm < 2; ++fm)
#pragma unroll
            for (int fn = 0; fn < 2; ++fn)
#pragma unroll
                for (int ks = 0; ks < 2; ++ks)
                    acc[mh * 2 + fm][nh * 2 + fn] =
                        __builtin_amdgcn_mfma_f32_16x16x32_bf16(
                            am[fm][ks], bn[fn][ks], acc[mh * 2 + fm][nh * 2 + fn], 0, 0, 0);
        __builtin_amdgcn_s_setprio(0);
    };

    // prologue: buf0 A(2) + buf0 B(4) + buf1 B(4) = 10; buf0 = oldest 6
    stA(0, 0, 0); stA(0, 1, 0);
    stB(0, 0, 0); stB(0, 1, 0);
    stB(1, 0, 1); stB(1, 1, 1);
    VMCNT4;
    BARRIER;

    for (int it = 0; it < NT2; ++it) {
        const int k1 = 2 * it + 1;
        const int k2 = (2 * it + 2 < NT) ? 2 * it + 2 : NT - 1;
        const int k3 = (2 * it + 3 < NT) ? 2 * it + 3 : NT - 1;
        rdA(0, 0); rdB(0, 0, bn0);
        stA(1, 0, k1);
        LGKM0; BARRIER;
        mq(0, 0, bn0);
        rdB(0, 1, bn1);
        stA(1, 1, k1);
        LGKM0; BARRIER;
        mq(0, 1, bn1);
        rdA(0, 1);
        stB(0, 0, k2);
        LGKM0; BARRIER;
        mq(1, 1, bn1);
        stB(0, 1, k2);
        VMCNT4; BARRIER;
        mq(1, 0, bn0);
        rdA(1, 0); rdB(1, 0, bn0);
        stA(0, 0, k2);
        LGKM0; BARRIER;
        mq(0, 0, bn0);
        rdB(1, 1, bn1);
        stA(0, 1, k2);
        LGKM0; BARRIER;
        mq(0, 1, bn1);
        rdA(1, 1);
        stB(1, 0, k3);
        LGKM0; BARRIER;
        mq(1, 1, bn1);
        stB(1, 1, k3);
        VMCNT4; BARRIER;
        mq(1, 0, bn0);
    }

    if (OUTBF) {
        unsigned short* sb = (unsigned short*)lds;   // [128][264]
#pragma unroll
        for (int j = 0; j < 4; ++j) {
            int colL = wc * 64 + j * 16 + llo;
            float bv = bias[n0 + colL];
#pragma unroll
            for (int i = 0; i < 4; ++i) {
                int rowL = wr * 64 + i * 16 + lhi * 4;
#pragma unroll
                for (int r = 0; r < 4; ++r) {
                    float o = acc[i][j][r] + bv;
                    if (MODE == 2) o = o / (1.0f + __expf(-1.702f * o));
                    sb[(rowL + r) * 264 + colL] = f2bf(o);
                }
            }
        }
        __syncthreads();
        const int l5 = lane & 31, lh2 = lane >> 5;
#pragma unroll
        for (int rr = 0; rr < 8; ++rr) {
            int rowL = rr * 16 + wid * 2 + lh2;
            u16x8 v = *(const u16x8*)&sb[rowL * 264 + l5 * 8];
            *(u16x8*)((unsigned short*)Cout + (size_t)(m0 + rowL) * N + n0 + l5 * 8) = v;
        }
    } else {
        float* sf = (float*)lds;                     // [64][260]
#pragma unroll
        for (int mh = 0; mh < 2; ++mh) {   // pass over 64-row halves (wr)
            if (mh) __syncthreads();
            if (wr == mh) {
#pragma unroll
                for (int j = 0; j < 4; ++j) {
                    int colL = wc * 64 + j * 16 + llo;
                    float bv = bias[n0 + colL];
#pragma unroll
                    for (int i = 0; i < 4; ++i) {
                        int rowL = i * 16 + lhi * 4;
#pragma unroll
                        for (int r = 0; r < 4; ++r)
                            sf[(rowL + r) * 260 + colL] = acc[i][j][r] + bv;
                    }
                }
            }
            __syncthreads();
#pragma unroll
            for (int rr = 0; rr < 8; ++rr) {
                int rowL = rr * 8 + wid;
                size_t gidx = (size_t)(m0 + mh * 64 + rowL) * N + n0 + lane * 4;
                f32x4 v = *(const f32x4*)&sf[rowL * 260 + lane * 4];
                if (MODE == 3) {
                    f32x4 rv = *(const f32x4*)&R[gidx];
                    v = v + rv;
                }
                *(f32x4*)((float*)Cout + gidx) = v;
            }
        }
    }
}

// ======================================================================
// MFMA attention: one block per (b,h), 4 waves, bf16 qkv input.
// ======================================================================
__global__ __launch_bounds__(256) void attn_mfma_kernel(
    const unsigned short* __restrict__ qkv, const int* __restrict__ amask,
    unsigned short* __restrict__ out)
{
    const int bh = blockIdx.x;
    const int b = bh >> 3;
    const int h = bh & 7;
    __shared__ __align__(16) char smem[68160];
    char* Qs = smem;
    char* Ks = smem + 10240;
    char* Vt = smem;
    char* Pb = smem + 20480;
    float* ss = (float*)(smem + 40960);
    float* padm = (float*)(smem + 67840);
    const int tid  = threadIdx.x;
    const int wid  = tid >> 6;
    const int lane = tid & 63;
    const int llo  = lane & 15;
    const int lhi  = lane >> 4;

    const size_t vbase = ((size_t)(b * SEQ)) * NQKV + 1024 + h * DHEAD;
    bf16x8 vr0, vr1, vr2;
    {
        int c0 = tid, c1 = tid + 256, c2 = tid + 512;
        vr0 = *(const bf16x8*)&qkv[vbase + (size_t)(c0 >> 3) * NQKV + (c0 & 7) * 8];
        vr1 = *(const bf16x8*)&qkv[vbase + (size_t)(c1 >> 3) * NQKV + (c1 & 7) * 8];
        if (c2 < 616)
            vr2 = *(const bf16x8*)&qkv[vbase + (size_t)(c2 >> 3) * NQKV + (c2 & 7) * 8];
    }

    if (tid < 160) {
        int r = tid >> 1, ch = 10 + (tid & 1);
        bf16x8 z;
#pragma unroll
        for (int j = 0; j < 8; ++j) z[j] = 0;
        *(bf16x8*)(Pb + r * 256 + ((ch ^ (r & 7)) * 16)) = z;
    }

    for (int f = tid; f < 640; f += 256) {
        int r = f >> 3, c = f & 7;
        bf16x8 pq, pk;
        if (r < SEQ) {
            size_t g = ((size_t)(b * SEQ + r)) * NQKV + h * DHEAD + c * 8;
            pq = *(const bf16x8*)&qkv[g];
            pk = *(const bf16x8*)&qkv[g + 512];
        } else {
#pragma unroll
            for (int j = 0; j < 8; ++j) { pq[j] = 0; pk[j] = 0; }
        }
        int byte = r * 128 + ((c * 16) ^ ((r & 7) << 4));
        *(bf16x8*)(Qs + byte) = pq;
        *(bf16x8*)(Ks + byte) = pk;
    }
    for (int s = tid; s < SEQ; s += 256)
        padm[s] = (1.0f - (float)amask[b * SEQ + s]) * NEGBIG;
    __syncthreads();

    for (int t = wid; t < 25; t += 4) {
        int rt = t / 5, ct = t % 5;
        int ar = rt * 16 + llo;
        int br = ct * 16 + llo;
        int aswz = (ar & 7) << 4;
        int bswz = (br & 7) << 4;
        bf16x8 a0 = *(const bf16x8*)(Qs + ar * 128 + ((lhi * 16) ^ aswz));
        bf16x8 a1 = *(const bf16x8*)(Qs + ar * 128 + (((lhi + 4) * 16) ^ aswz));
        bf16x8 b0 = *(const bf16x8*)(Ks + br * 128 + ((lhi * 16) ^ bswz));
        bf16x8 b1 = *(const bf16x8*)(Ks + br * 128 + (((lhi + 4) * 16) ^ bswz));
        f32x4 acc = (f32x4){0.f, 0.f, 0.f, 0.f};
        acc = __builtin_amdgcn_mfma_f32_16x16x32_bf16(a0, b0, acc, 0, 0, 0);
        acc = __builtin_amdgcn_mfma_f32_16x16x32_bf16(a1, b1, acc, 0, 0, 0);
        int ki = ct * 16 + llo;
#pragma unroll
        for (int r = 0; r < 4; ++r) {
            int qi = rt * 16 + lhi * 4 + r;
            ss[qi * 84 + ki] = (ki > qi || ki >= SEQ) ? NEGBIG : (acc[r] + padm[ki]);
        }
    }
    __syncthreads();

    {
        auto writeV = [&](int c, bf16x8 v) {
            int s = c >> 3, d8 = (c & 7) * 8;
            int chunk16 = (s >> 3) * 16, within = (s & 7) * 2;
#pragma unroll
            for (int j = 0; j < 8; ++j) {
                int d = d8 + j;
                *(short*)(Vt + d * 256 + (chunk16 ^ ((d & 7) << 4)) + within) = v[j];
            }
        };
        writeV(tid, vr0);
        writeV(tid + 256, vr1);
        if (tid + 512 < 616) writeV(tid + 512, vr2);
    }

    {
        const int g = lane >> 4;
        const int c = lane & 15;
#pragma unroll
        for (int pass = 0; pass < 5; ++pass) {
            int r = pass * 16 + wid * 4 + g;
            float v0 = ss[r * 84 + c];
            float v1 = ss[r * 84 + c + 16];
            float v2 = ss[r * 84 + c + 32];
            float v3 = ss[r * 84 + c + 48];
            float v4 = ss[r * 84 + c + 64];
            float m = fmaxf(fmaxf(fmaxf(v0, v1), fmaxf(v2, v3)), v4);
#pragma unroll
            for (int o = 8; o; o >>= 1) m = fmaxf(m, __shfl_xor(m, o));
            float e0 = __expf(v0 - m), e1 = __expf(v1 - m), e2 = __expf(v2 - m);
            float e3 = __expf(v3 - m), e4 = __expf(v4 - m);
            float tsum = e0 + e1 + e2 + e3 + e4;
#pragma unroll
            for (int o = 8; o; o >>= 1) tsum += __shfl_xor(tsum, o);
            float rinv = 1.0f / tsum;
            int rswz = (r & 7) << 4;
            int rb = r * 256;
            float ev[5] = {e0, e1, e2, e3, e4};
#pragma unroll
            for (int i = 0; i < 5; ++i) {
                int col = c + i * 16;
                *(short*)(Pb + rb + (((col >> 3) * 16) ^ rswz) + (col & 7) * 2) =
                    (short)f2bf(ev[i] * rinv);
            }
        }
    }
    __syncthreads();

    for (int t = wid; t < 20; t += 4) {
        int rt = t >> 2, ct = t & 3;
        int ar = rt * 16 + llo;
        int br = ct * 16 + llo;
        int aswz = (ar & 7) << 4;
        int bswz = (br & 7) << 4;
        f32x4 acc = (f32x4){0.f, 0.f, 0.f, 0.f};
#pragma unroll
        for (int kc = 0; kc < 3; ++kc) {
            bf16x8 af  = *(const bf16x8*)(Pb + ar * 256 + (((kc * 4 + lhi) * 16) ^ aswz));
            bf16x8 bf_ = *(const bf16x8*)(Vt + br * 256 + (((kc * 4 + lhi) * 16) ^ bswz));
            acc = __builtin_amdgcn_mfma_f32_16x16x32_bf16(af, bf_, acc, 0, 0, 0);
        }
        int d = ct * 16 + llo;
#pragma unroll
        for (int r = 0; r < 4; ++r) {
            int qi = rt * 16 + lhi * 4 + r;
            if (qi < SEQ)
                out[((size_t)(b * SEQ + qi)) * DMODEL + h * DHEAD + d] = f2bf(acc[r]);
        }
    }
}

// ======================================================================
// Pooled output
// ======================================================================
__global__ __launch_bounds__(64) void pool_kernel(
    const int* __restrict__ ids, const float* __restrict__ lh,
    float* __restrict__ pooled)
{
    int b = blockIdx.x;
    int ln = threadIdx.x;
    __shared__ int sidx;
    if (ln == 0) {
        int best = ids[b * SEQ]; int bi = 0;
        for (int s = 1; s < SEQ; ++s) {
            int vv = ids[b * SEQ + s];
            if (vv > best) { best = vv; bi = s; }
        }
        sidx = bi;
    }
    __syncthreads();
    const float* src = lh + ((size_t)(b * SEQ + sidx)) * DMODEL + ln * 8;
    float* dst = pooled + (size_t)b * DMODEL + ln * 8;
    float4 a = *(const float4*)src;
    float4 c = *(const float4*)(src + 4);
    *(float4*)dst       = a;
    *(float4*)(dst + 4) = c;
}

// ======================================================================
extern "C" void kernel_launch(void* const* d_in, const int* in_sizes, int n_in,
                              void* d_out, int out_size, void* d_ws, size_t ws_size,
                              hipStream_t stream) {
    const int*   ids   = (const int*)d_in[0];
    const int*   amask = (const int*)d_in[1];
    const float* tok   = (const float*)d_in[2];
    const float* pos   = (const float*)d_in[3];
    const float* ln1w  = (const float*)d_in[4];
    const float* ln1b  = (const float*)d_in[5];
    const float* qw    = (const float*)d_in[6];
    const float* qbias = (const float*)d_in[7];
    const float* kw    = (const float*)d_in[8];
    const float* kbias = (const float*)d_in[9];
    const float* vw    = (const float*)d_in[10];
    const float* vbias = (const float*)d_in[11];
    const float* ow    = (const float*)d_in[12];
    const float* obias = (const float*)d_in[13];
    const float* ln2w  = (const float*)d_in[14];
    const float* ln2b  = (const float*)d_in[15];
    const float* f1w   = (const float*)d_in[16];
    const float* f1b   = (const float*)d_in[17];
    const float* f2w   = (const float*)d_in[18];
    const float* f2b   = (const float*)d_in[19];
    const float* lnfw  = (const float*)d_in[20];
    const float* lnfb  = (const float*)d_in[21];

    char* p = (char*)d_ws;
    float* x = (float*)p;                      p += (size_t)NTOK * DMODEL * 4;
    unsigned short* hbuf = (unsigned short*)p; p += (size_t)NTOK * DMODEL * 2;
    unsigned short* qkvb = (unsigned short*)p; p += (size_t)NTOK * NQKV * 2;
    unsigned short* ao = (unsigned short*)p;   p += (size_t)NTOK * DMODEL * 2;
    unsigned short* ff = (unsigned short*)p;   p += (size_t)NTOK * DFF * 2;
    unsigned short* wqkv = (unsigned short*)p; p += (size_t)NLAYER * NQKV * DMODEL * 2;
    unsigned short* wo   = (unsigned short*)p; p += (size_t)NLAYER * DMODEL * DMODEL * 2;
    unsigned short* wf1  = (unsigned short*)p; p += (size_t)NLAYER * DFF * DMODEL * 2;
    unsigned short* wf2  = (unsigned short*)p; p += (size_t)NLAYER * DMODEL * DFF * 2;
    float* bqkv = (float*)p;                   p += (size_t)NLAYER * NQKV * 4;

    conv_qkv_kernel<<<(NLAYER * NQKV * DMODEL / 4) / 256, 256, 0, stream>>>(qw, kw, vw, wqkv);
    conv_kernel<<<(NLAYER * DMODEL * DMODEL / 4) / 256, 256, 0, stream>>>(ow, wo);
    conv_kernel<<<(NLAYER * DFF * DMODEL / 4) / 256, 256, 0, stream>>>(f1w, wf1);
    conv_kernel<<<(NLAYER * DMODEL * DFF / 4) / 256, 256, 0, stream>>>(f2w, wf2);
    bias_qkv_kernel<<<(NLAYER * NQKV) / 256, 256, 0, stream>>>(qbias, kbias, vbias, bqkv);

    embed_kernel<<<(NTOK * (DMODEL / 4) + 255) / 256, 256, 0, stream>>>(ids, tok, pos, x);

    const int MB = NTOK / 256;            // 77
    dim3 gqkv(MB * (NQKV / 256));         // 462
    dim3 g512h(2 * (NTOK / 128));         // 308  (128-M tiles x 2 N-tiles)
    dim3 g2048(MB * (DFF / 256));         // 616

    for (int l = 0; l < NLAYER; ++l) {
        const size_t wD2 = (size_t)l * DMODEL * DMODEL;
        const size_t wDF = (size_t)l * DFF * DMODEL;
        const size_t oD  = (size_t)l * DMODEL;
        const size_t oF  = (size_t)l * DFF;

        ln_kernel<true><<<NTOK / 4, 256, 0, stream>>>(x, ln1w + oD, ln1b + oD, hbuf, NTOK);
        gemm8_bf16<0, true><<<gqkv, 512, 0, stream>>>(
            hbuf, wqkv + (size_t)l * NQKV * DMODEL, bqkv + (size_t)l * NQKV, nullptr,
            qkvb, NTOK, NQKV, DMODEL, NQKV / 256);
        attn_mfma_kernel<<<BATCH * NHEAD, 256, 0, stream>>>(qkvb, amask, ao);
        gemm8h_bf16<3, false><<<g512h, 512, 0, stream>>>(
            ao, wo + wD2, obias + oD, x, x, NTOK, DMODEL, DMODEL, DMODEL / 256);
        ln_kernel<true><<<NTOK / 4, 256, 0, stream>>>(x, ln2w + oD, ln2b + oD, hbuf, NTOK);
        gemm8_bf16<2, true><<<g2048, 512, 0, stream>>>(
            hbuf, wf1 + wDF, f1b + oF, nullptr, ff, NTOK, DFF, DMODEL, DFF / 256);
        gemm8h_bf16<3, false><<<g512h, 512, 0, stream>>>(
            ff, wf2 + wDF, f2b + oD, x, x, NTOK, DMODEL, DFF, DMODEL / 256);
    }

    float* outf = (float*)d_out;
    ln_kernel<false><<<NTOK / 4, 256, 0, stream>>>(x, lnfw, lnfb, outf, NTOK);
    pool_kernel<<<BATCH, 64, 0, stream>>>(ids, outf, outf + (size_t)NTOK * DMODEL);
}

// Round 13
// 3358.651 us; speedup vs baseline: 1.0339x; 1.0339x over previous
//
#include <hip/hip_runtime.h>
#include <math.h>

// ---- Problem constants ----
constexpr int BATCH  = 256;
constexpr int SEQ    = 77;
constexpr int DMODEL = 512;
constexpr int NHEAD  = 8;
constexpr int DHEAD  = 64;
constexpr int DFF    = 2048;
constexpr int NLAYER = 12;
constexpr int NTOK   = BATCH * SEQ;      // 19712 = 77*256
constexpr int NQKV   = 3 * DMODEL;       // 1536
constexpr float NEGBIG = -3.402823466e38f;

typedef __attribute__((ext_vector_type(8))) short bf16x8;
typedef __attribute__((ext_vector_type(4))) float f32x4;
typedef __attribute__((ext_vector_type(8))) unsigned short u16x8;

typedef __attribute__((address_space(3))) unsigned char lds_u8;
typedef const __attribute__((address_space(1))) unsigned char g_u8;

__device__ __forceinline__ unsigned short f2bf(float f) {
    unsigned u = __float_as_uint(f);
    u = (u + 0x7FFF + ((u >> 16) & 1)) >> 16;
    return (unsigned short)u;
}

#define VMCNT4 asm volatile("s_waitcnt vmcnt(4)" ::: "memory")
#define LGKM0  asm volatile("s_waitcnt lgkmcnt(0)" ::: "memory")
#define SCHEDB __builtin_amdgcn_sched_barrier(0)
#define BARRIER do { SCHEDB; __builtin_amdgcn_s_barrier(); SCHEDB; } while (0)

// ======================================================================
// Weight conversion (runs every launch; deterministic).
// ======================================================================
__global__ __launch_bounds__(256) void conv_qkv_kernel(
    const float* __restrict__ qw, const float* __restrict__ kw,
    const float* __restrict__ vw, unsigned short* __restrict__ dst)
{
    int i4 = blockIdx.x * 256 + threadIdx.x;
    int e = i4 * 4;
    int l = e / (NQKV * DMODEL);
    int rem = e - l * (NQKV * DMODEL);
    int row = rem >> 9;
    int k   = rem & 511;
    const float* src;
    float scale = 1.0f;
    size_t lbase = (size_t)l * DMODEL * DMODEL;
    if (row < 512)       { src = qw + lbase + (size_t)row * DMODEL + k; scale = 0.125f; }
    else if (row < 1024) { src = kw + lbase + (size_t)(row - 512) * DMODEL + k; }
    else                 { src = vw + lbase + (size_t)(row - 1024) * DMODEL + k; }
    float4 v = *(const float4*)src;
    ushort4 o;
    o.x = f2bf(v.x * scale); o.y = f2bf(v.y * scale);
    o.z = f2bf(v.z * scale); o.w = f2bf(v.w * scale);
    *(ushort4*)&dst[e] = o;
}

__global__ __launch_bounds__(256) void conv_kernel(
    const float* __restrict__ src, unsigned short* __restrict__ dst)
{
    int e = (blockIdx.x * 256 + threadIdx.x) * 4;
    float4 v = *(const float4*)&src[e];
    ushort4 o;
    o.x = f2bf(v.x); o.y = f2bf(v.y); o.z = f2bf(v.z); o.w = f2bf(v.w);
    *(ushort4*)&dst[e] = o;
}

__global__ __launch_bounds__(256) void bias_qkv_kernel(
    const float* __restrict__ qb, const float* __restrict__ kb,
    const float* __restrict__ vb, float* __restrict__ dst)
{
    int e = blockIdx.x * 256 + threadIdx.x;
    int l = e / NQKV;
    int row = e - l * NQKV;
    float v;
    if (row < 512)       v = qb[l * DMODEL + row] * 0.125f;
    else if (row < 1024) v = kb[l * DMODEL + row - 512];
    else                 v = vb[l * DMODEL + row - 1024];
    dst[e] = v;
}

// ======================================================================
// Embedding
// ======================================================================
__global__ __launch_bounds__(256) void embed_kernel(
    const int* __restrict__ ids, const float* __restrict__ tok,
    const float* __restrict__ pos, float* __restrict__ x)
{
    int f = blockIdx.x * 256 + threadIdx.x;
    int total = NTOK * (DMODEL / 4);
    if (f >= total) return;
    int n  = f >> 7;
    int d4 = f & 127;
    int s  = n % SEQ;
    int id = ids[n];
    float4 t = *(const float4*)&tok[(size_t)id * DMODEL + d4 * 4];
    float4 p = *(const float4*)&pos[(size_t)s  * DMODEL + d4 * 4];
    float4 o; o.x = t.x + p.x; o.y = t.y + p.y; o.z = t.z + p.z; o.w = t.w + p.w;
    *(float4*)&x[(size_t)n * DMODEL + d4 * 4] = o;
}

// ======================================================================
// LayerNorm: one wave per row of 512.
// ======================================================================
template <bool BF16OUT>
__global__ __launch_bounds__(256) void ln_kernel(
    const float* __restrict__ x, const float* __restrict__ w,
    const float* __restrict__ b, void* __restrict__ out, int nrows)
{
    int row = blockIdx.x * 4 + (threadIdx.x >> 6);
    if (row >= nrows) return;
    int ln = threadIdx.x & 63;
    const float* xr = x + (size_t)row * DMODEL + ln * 8;
    float4 v0 = *(const float4*)xr;
    float4 v1 = *(const float4*)(xr + 4);
    float va[8] = {v0.x, v0.y, v0.z, v0.w, v1.x, v1.y, v1.z, v1.w};
    float sum = 0.f, sq = 0.f;
#pragma unroll
    for (int j = 0; j < 8; ++j) { sum += va[j]; sq = fmaf(va[j], va[j], sq); }
#pragma unroll
    for (int o = 32; o; o >>= 1) { sum += __shfl_xor(sum, o); sq += __shfl_xor(sq, o); }
    float mu  = sum * (1.0f / DMODEL);
    float var = sq * (1.0f / DMODEL) - mu * mu;
    var = fmaxf(var, 0.0f);
    float inv = 1.0f / sqrtf(var + 1e-5f);
    const float* wp = w + ln * 8;
    const float* bp = b + ln * 8;
    float o8[8];
#pragma unroll
    for (int j = 0; j < 8; ++j) o8[j] = (va[j] - mu) * inv * wp[j] + bp[j];
    if (BF16OUT) {
        u16x8 pk;
#pragma unroll
        for (int j = 0; j < 8; ++j) pk[j] = f2bf(o8[j]);
        *(u16x8*)((unsigned short*)out + (size_t)row * DMODEL + ln * 8) = pk;
    } else {
        float* op = (float*)out + (size_t)row * DMODEL + ln * 8;
        *(float4*)op       = make_float4(o8[0], o8[1], o8[2], o8[3]);
        *(float4*)(op + 4) = make_float4(o8[4], o8[5], o8[6], o8[7]);
    }
}

// ======================================================================
// 8-phase bf16 MFMA GEMM: 256x256 tile, BK=64, 512 thr (8 waves 2Mx4N).
// Counted vmcnt(4) at P4/P8. Padded LDS epilogue (zero staging conflicts).
// MODE 0:+bias; 2:quickGELU(+bias); 3:+bias+R.
// ======================================================================
template <int MODE, bool OUTBF>
__global__ __launch_bounds__(512, 2) void gemm8_bf16(
    const unsigned short* __restrict__ A, const unsigned short* __restrict__ W,
    const float* __restrict__ bias, const float* __restrict__ R,
    void* __restrict__ Cout, int M, int N, int K, int gx)
{
    __shared__ __align__(16) char lds[135168];   // K-loop uses [0,128K)
    const int nwg = gridDim.x;
    const int wg  = blockIdx.x;
    const int q8  = nwg >> 3, r8 = nwg & 7;
    const int xcd = wg & 7, pos = wg >> 3;
    const int start = (xcd < r8) ? xcd * (q8 + 1) : r8 * (q8 + 1) + (xcd - r8) * q8;
    const int newid = start + pos;
    const int by = newid / gx;
    const int bx = newid - by * gx;
    const int m0 = by * 256;
    const int n0 = bx * 256;

    const int tid  = threadIdx.x;
    const int wid  = tid >> 6;
    const int lane = tid & 63;
    const int wr   = wid >> 2;
    const int wc   = wid & 3;
    const int lhi  = lane >> 4;
    const int llo  = lane & 15;

    const int srow  = tid >> 3;
    const int cglob = (tid & 7) ^ (srow & 7);
    const unsigned short* Ap = A + (size_t)(m0 + srow) * K + cglob * 8;
    const unsigned short* Wp = W + (size_t)(n0 + srow) * K + cglob * 8;
    const int NT  = K >> 6;
    const int NT2 = K >> 7;

    const int cb0 = ((0 * 4 + lhi) ^ (llo & 7)) * 16;
    const int cb1 = ((1 * 4 + lhi) ^ (llo & 7)) * 16;
    const int rbA0 = (wr * 128 + 0 * 64 + llo) * 128;
    const int rbA1 = (wr * 128 + 1 * 64 + llo) * 128;
    const int rbB0 = (wc * 64 + 0 * 32 + llo) * 128;
    const int rbB1 = (wc * 64 + 1 * 32 + llo) * 128;

    f32x4 acc[8][4];
#pragma unroll
    for (int i = 0; i < 8; ++i)
#pragma unroll
        for (int j = 0; j < 4; ++j) acc[i][j] = (f32x4){0.f, 0.f, 0.f, 0.f};

    bf16x8 am[4][2], bn0[2][2], bn1[2][2];

    auto stA = [&](int b, int h, int kt) {
#pragma unroll
        for (int i = h * 2; i < h * 2 + 2; ++i)
            __builtin_amdgcn_global_load_lds(
                (g_u8*)(Ap + (size_t)i * 64 * K + kt * 64),
                (lds_u8*)(lds + b * 32768 + i * 8192 + wid * 1024), 16, 0, 0);
    };
    auto stB = [&](int b, int h, int kt) {
#pragma unroll
        for (int i = h * 2; i < h * 2 + 2; ++i)
            __builtin_amdgcn_global_load_lds(
                (g_u8*)(Wp + (size_t)i * 64 * K + kt * 64),
                (lds_u8*)(lds + 65536 + b * 32768 + i * 8192 + wid * 1024), 16, 0, 0);
    };
    auto rdA = [&](int b, int mh) {
        int base = b * 32768 + (mh ? rbA1 : rbA0);
#pragma unroll
        for (int fm = 0; fm < 4; ++fm) {
            am[fm][0] = *(const bf16x8*)(lds + base + fm * 2048 + cb0);
            am[fm][1] = *(const bf16x8*)(lds + base + fm * 2048 + cb1);
        }
    };
    auto rdB = [&](int b, int nh, bf16x8 (&bn)[2][2]) {
        int base = 65536 + b * 32768 + (nh ? rbB1 : rbB0);
#pragma unroll
        for (int fn = 0; fn < 2; ++fn) {
            bn[fn][0] = *(const bf16x8*)(lds + base + fn * 2048 + cb0);
            bn[fn][1] = *(const bf16x8*)(lds + base + fn * 2048 + cb1);
        }
    };
    auto mq = [&](int mh, int nh, bf16x8 (&bn)[2][2]) {
        __builtin_amdgcn_s_setprio(1);
#pragma unroll
        for (int fm = 0; fm < 4; ++fm)
#pragma unroll
            for (int fn = 0; fn < 2; ++fn)
#pragma unroll
                for (int ks = 0; ks < 2; ++ks)
                    acc[mh * 4 + fm][nh * 2 + fn] =
                        __builtin_amdgcn_mfma_f32_16x16x32_bf16(
                            am[fm][ks], bn[fn][ks], acc[mh * 4 + fm][nh * 2 + fn], 0, 0, 0);
        __builtin_amdgcn_s_setprio(0);
    };

    stA(0, 0, 0); stA(0, 1, 0);
    stB(0, 0, 0); stB(0, 1, 0);
    stB(1, 0, 1); stB(1, 1, 1);
    VMCNT4;
    BARRIER;

    for (int it = 0; it < NT2; ++it) {
        const int k1 = 2 * it + 1;
        const int k2 = (2 * it + 2 < NT) ? 2 * it + 2 : NT - 1;
        const int k3 = (2 * it + 3 < NT) ? 2 * it + 3 : NT - 1;
        rdA(0, 0); rdB(0, 0, bn0);
        stA(1, 0, k1);
        LGKM0; BARRIER;
        mq(0, 0, bn0);
        rdB(0, 1, bn1);
        stA(1, 1, k1);
        LGKM0; BARRIER;
        mq(0, 1, bn1);
        rdA(0, 1);
        stB(0, 0, k2);
        LGKM0; BARRIER;
        mq(1, 1, bn1);
        stB(0, 1, k2);
        VMCNT4; BARRIER;
        mq(1, 0, bn0);
        rdA(1, 0); rdB(1, 0, bn0);
        stA(0, 0, k2);
        LGKM0; BARRIER;
        mq(0, 0, bn0);
        rdB(1, 1, bn1);
        stA(0, 1, k2);
        LGKM0; BARRIER;
        mq(0, 1, bn1);
        rdA(1, 1);
        stB(1, 0, k3);
        LGKM0; BARRIER;
        mq(1, 1, bn1);
        stB(1, 1, k3);
        VMCNT4; BARRIER;
        mq(1, 0, bn0);
    }

    if (OUTBF) {
        unsigned short* sb = (unsigned short*)lds;   // [256][264]
#pragma unroll
        for (int j = 0; j < 4; ++j) {
            int colL = wc * 64 + j * 16 + llo;
            float bv = bias[n0 + colL];
#pragma unroll
            for (int i = 0; i < 8; ++i) {
                int rowL = wr * 128 + i * 16 + lhi * 4;
#pragma unroll
                for (int r = 0; r < 4; ++r) {
                    float o = acc[i][j][r] + bv;
                    if (MODE == 2) o = o / (1.0f + __expf(-1.702f * o));
                    sb[(rowL + r) * 264 + colL] = f2bf(o);
                }
            }
        }
        __syncthreads();
        const int l5 = lane & 31, lh2 = lane >> 5;
#pragma unroll
        for (int rr = 0; rr < 16; ++rr) {
            int rowL = rr * 16 + wid * 2 + lh2;
            u16x8 v = *(const u16x8*)&sb[rowL * 264 + l5 * 8];
            *(u16x8*)((unsigned short*)Cout + (size_t)(m0 + rowL) * N + n0 + l5 * 8) = v;
        }
    } else {
        float* sf = (float*)lds;                     // [128][260]
#pragma unroll
        for (int mh = 0; mh < 2; ++mh) {
            if (mh) __syncthreads();
            if (wr == mh) {
#pragma unroll
                for (int j = 0; j < 4; ++j) {
                    int colL = wc * 64 + j * 16 + llo;
                    float bv = bias[n0 + colL];
#pragma unroll
                    for (int i = 0; i < 8; ++i) {
                        int rowL = i * 16 + lhi * 4;
#pragma unroll
                        for (int r = 0; r < 4; ++r)
                            sf[(rowL + r) * 260 + colL] = acc[i][j][r] + bv;
                    }
                }
            }
            __syncthreads();
#pragma unroll
            for (int rr = 0; rr < 16; ++rr) {
                int rowL = rr * 8 + wid;
                size_t gidx = (size_t)(m0 + mh * 128 + rowL) * N + n0 + lane * 4;
                f32x4 v = *(const f32x4*)&sf[rowL * 260 + lane * 4];
                if (MODE == 3) {
                    f32x4 rv = *(const f32x4*)&R[gidx];
                    v = v + rv;
                }
                *(f32x4*)((float*)Cout + gidx) = v;
            }
        }
    }
}

// ======================================================================
// MFMA attention: one block per (b,h), 4 waves, bf16 qkv input.
// 16-lane-group softmax, V reg-prefetch, P cols 77..95 exactly zero.
// ======================================================================
__global__ __launch_bounds__(256) void attn_mfma_kernel(
    const unsigned short* __restrict__ qkv, const int* __restrict__ amask,
    unsigned short* __restrict__ out)
{
    const int bh = blockIdx.x;
    const int b = bh >> 3;
    const int h = bh & 7;
    __shared__ __align__(16) char smem[68160];
    char* Qs = smem;
    char* Ks = smem + 10240;
    char* Vt = smem;
    char* Pb = smem + 20480;
    float* ss = (float*)(smem + 40960);
    float* padm = (float*)(smem + 67840);
    const int tid  = threadIdx.x;
    const int wid  = tid >> 6;
    const int lane = tid & 63;
    const int llo  = lane & 15;
    const int lhi  = lane >> 4;

    const size_t vbase = ((size_t)(b * SEQ)) * NQKV + 1024 + h * DHEAD;
    bf16x8 vr0, vr1, vr2;
    {
        int c0 = tid, c1 = tid + 256, c2 = tid + 512;
        vr0 = *(const bf16x8*)&qkv[vbase + (size_t)(c0 >> 3) * NQKV + (c0 & 7) * 8];
        vr1 = *(const bf16x8*)&qkv[vbase + (size_t)(c1 >> 3) * NQKV + (c1 & 7) * 8];
        if (c2 < 616)
            vr2 = *(const bf16x8*)&qkv[vbase + (size_t)(c2 >> 3) * NQKV + (c2 & 7) * 8];
    }

    if (tid < 160) {
        int r = tid >> 1, ch = 10 + (tid & 1);
        bf16x8 z;
#pragma unroll
        for (int j = 0; j < 8; ++j) z[j] = 0;
        *(bf16x8*)(Pb + r * 256 + ((ch ^ (r & 7)) * 16)) = z;
    }

    for (int f = tid; f < 640; f += 256) {
        int r = f >> 3, c = f & 7;
        bf16x8 pq, pk;
        if (r < SEQ) {
            size_t g = ((size_t)(b * SEQ + r)) * NQKV + h * DHEAD + c * 8;
            pq = *(const bf16x8*)&qkv[g];
            pk = *(const bf16x8*)&qkv[g + 512];
        } else {
#pragma unroll
            for (int j = 0; j < 8; ++j) { pq[j] = 0; pk[j] = 0; }
        }
        int byte = r * 128 + ((c * 16) ^ ((r & 7) << 4));
        *(bf16x8*)(Qs + byte) = pq;
        *(bf16x8*)(Ks + byte) = pk;
    }
    for (int s = tid; s < SEQ; s += 256)
        padm[s] = (1.0f - (float)amask[b * SEQ + s]) * NEGBIG;
    __syncthreads();

    for (int t = wid; t < 25; t += 4) {
        int rt = t / 5, ct = t % 5;
        int ar = rt * 16 + llo;
        int br = ct * 16 + llo;
        int aswz = (ar & 7) << 4;
        int bswz = (br & 7) << 4;
        bf16x8 a0 = *(const bf16x8*)(Qs + ar * 128 + ((lhi * 16) ^ aswz));
        bf16x8 a1 = *(const bf16x8*)(Qs + ar * 128 + (((lhi + 4) * 16) ^ aswz));
        bf16x8 b0 = *(const bf16x8*)(Ks + br * 128 + ((lhi * 16) ^ bswz));
        bf16x8 b1 = *(const bf16x8*)(Ks + br * 128 + (((lhi + 4) * 16) ^ bswz));
        f32x4 acc = (f32x4){0.f, 0.f, 0.f, 0.f};
        acc = __builtin_amdgcn_mfma_f32_16x16x32_bf16(a0, b0, acc, 0, 0, 0);
        acc = __builtin_amdgcn_mfma_f32_16x16x32_bf16(a1, b1, acc, 0, 0, 0);
        int ki = ct * 16 + llo;
#pragma unroll
        for (int r = 0; r < 4; ++r) {
            int qi = rt * 16 + lhi * 4 + r;
            ss[qi * 84 + ki] = (ki > qi || ki >= SEQ) ? NEGBIG : (acc[r] + padm[ki]);
        }
    }
    __syncthreads();

    {
        auto writeV = [&](int c, bf16x8 v) {
            int s = c >> 3, d8 = (c & 7) * 8;
            int chunk16 = (s >> 3) * 16, within = (s & 7) * 2;
#pragma unroll
            for (int j = 0; j < 8; ++j) {
                int d = d8 + j;
                *(short*)(Vt + d * 256 + (chunk16 ^ ((d & 7) << 4)) + within) = v[j];
            }
        };
        writeV(tid, vr0);
        writeV(tid + 256, vr1);
        if (tid + 512 < 616) writeV(tid + 512, vr2);
    }

    {
        const int g = lane >> 4;
        const int c = lane & 15;
#pragma unroll
        for (int pass = 0; pass < 5; ++pass) {
            int r = pass * 16 + wid * 4 + g;
            float v0 = ss[r * 84 + c];
            float v1 = ss[r * 84 + c + 16];
            float v2 = ss[r * 84 + c + 32];
            float v3 = ss[r * 84 + c + 48];
            float v4 = ss[r * 84 + c + 64];
            float m = fmaxf(fmaxf(fmaxf(v0, v1), fmaxf(v2, v3)), v4);
#pragma unroll
            for (int o = 8; o; o >>= 1) m = fmaxf(m, __shfl_xor(m, o));
            float e0 = __expf(v0 - m), e1 = __expf(v1 - m), e2 = __expf(v2 - m);
            float e3 = __expf(v3 - m), e4 = __expf(v4 - m);
            float tsum = e0 + e1 + e2 + e3 + e4;
#pragma unroll
            for (int o = 8; o; o >>= 1) tsum += __shfl_xor(tsum, o);
            float rinv = 1.0f / tsum;
            int rswz = (r & 7) << 4;
            int rb = r * 256;
            float ev[5] = {e0, e1, e2, e3, e4};
#pragma unroll
            for (int i = 0; i < 5; ++i) {
                int col = c + i * 16;
                *(short*)(Pb + rb + (((col >> 3) * 16) ^ rswz) + (col & 7) * 2) =
                    (short)f2bf(ev[i] * rinv);
            }
        }
    }
    __syncthreads();

    for (int t = wid; t < 20; t += 4) {
        int rt = t >> 2, ct = t & 3;
        int ar = rt * 16 + llo;
        int br = ct * 16 + llo;
        int aswz = (ar & 7) << 4;
        int bswz = (br & 7) << 4;
        f32x4 acc = (f32x4){0.f, 0.f, 0.f, 0.f};
#pragma unroll
        for (int kc = 0; kc < 3; ++kc) {
            bf16x8 af  = *(const bf16x8*)(Pb + ar * 256 + (((kc * 4 + lhi) * 16) ^ aswz));
            bf16x8 bf_ = *(const bf16x8*)(Vt + br * 256 + (((kc * 4 + lhi) * 16) ^ bswz));
            acc = __builtin_amdgcn_mfma_f32_16x16x32_bf16(af, bf_, acc, 0, 0, 0);
        }
        int d = ct * 16 + llo;
#pragma unroll
        for (int r = 0; r < 4; ++r) {
            int qi = rt * 16 + lhi * 4 + r;
            if (qi < SEQ)
                out[((size_t)(b * SEQ + qi)) * DMODEL + h * DHEAD + d] = f2bf(acc[r]);
        }
    }
}

// ======================================================================
// Pooled output
// ======================================================================
__global__ __launch_bounds__(64) void pool_kernel(
    const int* __restrict__ ids, const float* __restrict__ lh,
    float* __restrict__ pooled)
{
    int b = blockIdx.x;
    int ln = threadIdx.x;
    __shared__ int sidx;
    if (ln == 0) {
        int best = ids[b * SEQ]; int bi = 0;
        for (int s = 1; s < SEQ; ++s) {
            int vv = ids[b * SEQ + s];
            if (vv > best) { best = vv; bi = s; }
        }
        sidx = bi;
    }
    __syncthreads();
    const float* src = lh + ((size_t)(b * SEQ + sidx)) * DMODEL + ln * 8;
    float* dst = pooled + (size_t)b * DMODEL + ln * 8;
    float4 a = *(const float4*)src;
    float4 c = *(const float4*)(src + 4);
    *(float4*)dst       = a;
    *(float4*)(dst + 4) = c;
}

// ======================================================================
extern "C" void kernel_launch(void* const* d_in, const int* in_sizes, int n_in,
                              void* d_out, int out_size, void* d_ws, size_t ws_size,
                              hipStream_t stream) {
    const int*   ids   = (const int*)d_in[0];
    const int*   amask = (const int*)d_in[1];
    const float* tok   = (const float*)d_in[2];
    const float* pos   = (const float*)d_in[3];
    const float* ln1w  = (const float*)d_in[4];
    const float* ln1b  = (const float*)d_in[5];
    const float* qw    = (const float*)d_in[6];
    const float* qbias = (const float*)d_in[7];
    const float* kw    = (const float*)d_in[8];
    const float* kbias = (const float*)d_in[9];
    const float* vw    = (const float*)d_in[10];
    const float* vbias = (const float*)d_in[11];
    const float* ow    = (const float*)d_in[12];
    const float* obias = (const float*)d_in[13];
    const float* ln2w  = (const float*)d_in[14];
    const float* ln2b  = (const float*)d_in[15];
    const float* f1w   = (const float*)d_in[16];
    const float* f1b   = (const float*)d_in[17];
    const float* f2w   = (const float*)d_in[18];
    const float* f2b   = (const float*)d_in[19];
    const float* lnfw  = (const float*)d_in[20];
    const float* lnfb  = (const float*)d_in[21];

    char* p = (char*)d_ws;
    float* x = (float*)p;                      p += (size_t)NTOK * DMODEL * 4;
    unsigned short* hbuf = (unsigned short*)p; p += (size_t)NTOK * DMODEL * 2;
    unsigned short* qkvb = (unsigned short*)p; p += (size_t)NTOK * NQKV * 2;
    unsigned short* ao = (unsigned short*)p;   p += (size_t)NTOK * DMODEL * 2;
    unsigned short* ff = (unsigned short*)p;   p += (size_t)NTOK * DFF * 2;
    unsigned short* wqkv = (unsigned short*)p; p += (size_t)NLAYER * NQKV * DMODEL * 2;
    unsigned short* wo   = (unsigned short*)p; p += (size_t)NLAYER * DMODEL * DMODEL * 2;
    unsigned short* wf1  = (unsigned short*)p; p += (size_t)NLAYER * DFF * DMODEL * 2;
    unsigned short* wf2  = (unsigned short*)p; p += (size_t)NLAYER * DMODEL * DFF * 2;
    float* bqkv = (float*)p;                   p += (size_t)NLAYER * NQKV * 4;

    conv_qkv_kernel<<<(NLAYER * NQKV * DMODEL / 4) / 256, 256, 0, stream>>>(qw, kw, vw, wqkv);
    conv_kernel<<<(NLAYER * DMODEL * DMODEL / 4) / 256, 256, 0, stream>>>(ow, wo);
    conv_kernel<<<(NLAYER * DFF * DMODEL / 4) / 256, 256, 0, stream>>>(f1w, wf1);
    conv_kernel<<<(NLAYER * DMODEL * DFF / 4) / 256, 256, 0, stream>>>(f2w, wf2);
    bias_qkv_kernel<<<(NLAYER * NQKV) / 256, 256, 0, stream>>>(qbias, kbias, vbias, bqkv);

    embed_kernel<<<(NTOK * (DMODEL / 4) + 255) / 256, 256, 0, stream>>>(ids, tok, pos, x);

    const int MB = NTOK / 256;            // 77
    dim3 gqkv(MB * (NQKV / 256));         // 462
    dim3 g512(MB * (DMODEL / 256));       // 154
    dim3 g2048(MB * (DFF / 256));         // 616

    for (int l = 0; l < NLAYER; ++l) {
        const size_t wD2 = (size_t)l * DMODEL * DMODEL;
        const size_t wDF = (size_t)l * DFF * DMODEL;
        const size_t oD  = (size_t)l * DMODEL;
        const size_t oF  = (size_t)l * DFF;

        ln_kernel<true><<<NTOK / 4, 256, 0, stream>>>(x, ln1w + oD, ln1b + oD, hbuf, NTOK);
        gemm8_bf16<0, true><<<gqkv, 512, 0, stream>>>(
            hbuf, wqkv + (size_t)l * NQKV * DMODEL, bqkv + (size_t)l * NQKV, nullptr,
            qkvb, NTOK, NQKV, DMODEL, NQKV / 256);
        attn_mfma_kernel<<<BATCH * NHEAD, 256, 0, stream>>>(qkvb, amask, ao);
        gemm8_bf16<3, false><<<g512, 512, 0, stream>>>(
            ao, wo + wD2, obias + oD, x, x, NTOK, DMODEL, DMODEL, DMODEL / 256);
        ln_kernel<true><<<NTOK / 4, 256, 0, stream>>>(x, ln2w + oD, ln2b + oD, hbuf, NTOK);
        gemm8_bf16<2, true><<<g2048, 512, 0, stream>>>(
            hbuf, wf1 + wDF, f1b + oF, nullptr, ff, NTOK, DFF, DMODEL, DFF / 256);
        gemm8_bf16<3, false><<<g512, 512, 0, stream>>>(
            ff, wf2 + wDF, f2b + oD, x, x, NTOK, DMODEL, DFF, DMODEL / 256);
    }

    float* outf = (float*)d_out;
    ln_kernel<false><<<NTOK / 4, 256, 0, stream>>>(x, lnfw, lnfb, outf, NTOK);
    pool_kernel<<<BATCH, 64, 0, stream>>>(ids, outf, outf + (size_t)NTOK * DMODEL);
}

// Round 14
// 3118.331 us; speedup vs baseline: 1.1136x; 1.0771x over previous
//
#include <hip/hip_runtime.h>
#include <math.h>

// ---- Problem constants ----
constexpr int BATCH  = 256;
constexpr int SEQ    = 77;
constexpr int DMODEL = 512;
constexpr int NHEAD  = 8;
constexpr int DHEAD  = 64;
constexpr int DFF    = 2048;
constexpr int NLAYER = 12;
constexpr int NTOK   = BATCH * SEQ;      // 19712 = 77*256
constexpr int NQKV   = 3 * DMODEL;       // 1536
constexpr float NEGBIG = -3.402823466e38f;

typedef __attribute__((ext_vector_type(8))) short bf16x8;
typedef __attribute__((ext_vector_type(4))) float f32x4;
typedef __attribute__((ext_vector_type(8))) unsigned short u16x8;

typedef __attribute__((address_space(3))) unsigned char lds_u8;
typedef const __attribute__((address_space(1))) unsigned char g_u8;

__device__ __forceinline__ unsigned short f2bf(float f) {
    unsigned u = __float_as_uint(f);
    u = (u + 0x7FFF + ((u >> 16) & 1)) >> 16;
    return (unsigned short)u;
}
__device__ __forceinline__ float bf2f(unsigned short v) {
    return __uint_as_float((unsigned)v << 16);
}

#define VMCNT4 asm volatile("s_waitcnt vmcnt(4)" ::: "memory")
#define LGKM0  asm volatile("s_waitcnt lgkmcnt(0)" ::: "memory")
#define SCHEDB __builtin_amdgcn_sched_barrier(0)
#define BARRIER do { SCHEDB; __builtin_amdgcn_s_barrier(); SCHEDB; } while (0)

// ======================================================================
// Weight conversion (runs every launch; deterministic).
// ======================================================================
__global__ __launch_bounds__(256) void conv_qkv_kernel(
    const float* __restrict__ qw, const float* __restrict__ kw,
    const float* __restrict__ vw, unsigned short* __restrict__ dst)
{
    int i4 = blockIdx.x * 256 + threadIdx.x;
    int e = i4 * 4;
    int l = e / (NQKV * DMODEL);
    int rem = e - l * (NQKV * DMODEL);
    int row = rem >> 9;
    int k   = rem & 511;
    const float* src;
    float scale = 1.0f;
    size_t lbase = (size_t)l * DMODEL * DMODEL;
    if (row < 512)       { src = qw + lbase + (size_t)row * DMODEL + k; scale = 0.125f; }
    else if (row < 1024) { src = kw + lbase + (size_t)(row - 512) * DMODEL + k; }
    else                 { src = vw + lbase + (size_t)(row - 1024) * DMODEL + k; }
    float4 v = *(const float4*)src;
    ushort4 o;
    o.x = f2bf(v.x * scale); o.y = f2bf(v.y * scale);
    o.z = f2bf(v.z * scale); o.w = f2bf(v.w * scale);
    *(ushort4*)&dst[e] = o;
}

__global__ __launch_bounds__(256) void conv_kernel(
    const float* __restrict__ src, unsigned short* __restrict__ dst)
{
    int e = (blockIdx.x * 256 + threadIdx.x) * 4;
    float4 v = *(const float4*)&src[e];
    ushort4 o;
    o.x = f2bf(v.x); o.y = f2bf(v.y); o.z = f2bf(v.z); o.w = f2bf(v.w);
    *(ushort4*)&dst[e] = o;
}

__global__ __launch_bounds__(256) void bias_qkv_kernel(
    const float* __restrict__ qb, const float* __restrict__ kb,
    const float* __restrict__ vb, float* __restrict__ dst)
{
    int e = blockIdx.x * 256 + threadIdx.x;
    int l = e / NQKV;
    int row = e - l * NQKV;
    float v;
    if (row < 512)       v = qb[l * DMODEL + row] * 0.125f;
    else if (row < 1024) v = kb[l * DMODEL + row - 512];
    else                 v = vb[l * DMODEL + row - 1024];
    dst[e] = v;
}

// ======================================================================
// Embedding -> bf16 residual stream
// ======================================================================
__global__ __launch_bounds__(256) void embed_kernel(
    const int* __restrict__ ids, const float* __restrict__ tok,
    const float* __restrict__ pos, unsigned short* __restrict__ x)
{
    int f = blockIdx.x * 256 + threadIdx.x;
    int total = NTOK * (DMODEL / 4);
    if (f >= total) return;
    int n  = f >> 7;
    int d4 = f & 127;
    int s  = n % SEQ;
    int id = ids[n];
    float4 t = *(const float4*)&tok[(size_t)id * DMODEL + d4 * 4];
    float4 p = *(const float4*)&pos[(size_t)s  * DMODEL + d4 * 4];
    ushort4 o;
    o.x = f2bf(t.x + p.x); o.y = f2bf(t.y + p.y);
    o.z = f2bf(t.z + p.z); o.w = f2bf(t.w + p.w);
    *(ushort4*)&x[(size_t)n * DMODEL + d4 * 4] = o;
}

// ======================================================================
// LayerNorm: one wave per row of 512; bf16 input, bf16 or f32 output.
// ======================================================================
template <bool BF16OUT>
__global__ __launch_bounds__(256) void ln_kernel(
    const unsigned short* __restrict__ x, const float* __restrict__ w,
    const float* __restrict__ b, void* __restrict__ out, int nrows)
{
    int row = blockIdx.x * 4 + (threadIdx.x >> 6);
    if (row >= nrows) return;
    int ln = threadIdx.x & 63;
    u16x8 xv = *(const u16x8*)(x + (size_t)row * DMODEL + ln * 8);
    float va[8];
#pragma unroll
    for (int j = 0; j < 8; ++j) va[j] = bf2f(xv[j]);
    float sum = 0.f, sq = 0.f;
#pragma unroll
    for (int j = 0; j < 8; ++j) { sum += va[j]; sq = fmaf(va[j], va[j], sq); }
#pragma unroll
    for (int o = 32; o; o >>= 1) { sum += __shfl_xor(sum, o); sq += __shfl_xor(sq, o); }
    float mu  = sum * (1.0f / DMODEL);
    float var = sq * (1.0f / DMODEL) - mu * mu;
    var = fmaxf(var, 0.0f);
    float inv = 1.0f / sqrtf(var + 1e-5f);
    const float* wp = w + ln * 8;
    const float* bp = b + ln * 8;
    float o8[8];
#pragma unroll
    for (int j = 0; j < 8; ++j) o8[j] = (va[j] - mu) * inv * wp[j] + bp[j];
    if (BF16OUT) {
        u16x8 pk;
#pragma unroll
        for (int j = 0; j < 8; ++j) pk[j] = f2bf(o8[j]);
        *(u16x8*)((unsigned short*)out + (size_t)row * DMODEL + ln * 8) = pk;
    } else {
        float* op = (float*)out + (size_t)row * DMODEL + ln * 8;
        *(float4*)op       = make_float4(o8[0], o8[1], o8[2], o8[3]);
        *(float4*)(op + 4) = make_float4(o8[4], o8[5], o8[6], o8[7]);
    }
}

// ======================================================================
// 8-phase bf16 MFMA GEMM: 256x256 tile, BK=64, 512 thr (8 waves 2Mx4N).
// Counted vmcnt(4) at P4/P8. Padded LDS epilogue.
// MODE 0: +bias (bf16 out); 2: quickGELU(+bias) (bf16 out);
// MODE 3: +bias + bf16 R -> bf16 out (f32 staging, residual added f32).
// ======================================================================
template <int MODE>
__global__ __launch_bounds__(512, 2) void gemm8_bf16(
    const unsigned short* __restrict__ A, const unsigned short* __restrict__ W,
    const float* __restrict__ bias, const unsigned short* __restrict__ R,
    void* __restrict__ Cout, int M, int N, int K, int gx)
{
    __shared__ __align__(16) char lds[135168];   // K-loop uses [0,128K)
    const int nwg = gridDim.x;
    const int wg  = blockIdx.x;
    const int q8  = nwg >> 3, r8 = nwg & 7;
    const int xcd = wg & 7, pos = wg >> 3;
    const int start = (xcd < r8) ? xcd * (q8 + 1) : r8 * (q8 + 1) + (xcd - r8) * q8;
    const int newid = start + pos;
    const int by = newid / gx;
    const int bx = newid - by * gx;
    const int m0 = by * 256;
    const int n0 = bx * 256;

    const int tid  = threadIdx.x;
    const int wid  = tid >> 6;
    const int lane = tid & 63;
    const int wr   = wid >> 2;
    const int wc   = wid & 3;
    const int lhi  = lane >> 4;
    const int llo  = lane & 15;

    const int srow  = tid >> 3;
    const int cglob = (tid & 7) ^ (srow & 7);
    const unsigned short* Ap = A + (size_t)(m0 + srow) * K + cglob * 8;
    const unsigned short* Wp = W + (size_t)(n0 + srow) * K + cglob * 8;
    const int NT  = K >> 6;
    const int NT2 = K >> 7;

    const int cb0 = ((0 * 4 + lhi) ^ (llo & 7)) * 16;
    const int cb1 = ((1 * 4 + lhi) ^ (llo & 7)) * 16;
    const int rbA0 = (wr * 128 + 0 * 64 + llo) * 128;
    const int rbA1 = (wr * 128 + 1 * 64 + llo) * 128;
    const int rbB0 = (wc * 64 + 0 * 32 + llo) * 128;
    const int rbB1 = (wc * 64 + 1 * 32 + llo) * 128;

    f32x4 acc[8][4];
#pragma unroll
    for (int i = 0; i < 8; ++i)
#pragma unroll
        for (int j = 0; j < 4; ++j) acc[i][j] = (f32x4){0.f, 0.f, 0.f, 0.f};

    bf16x8 am[4][2], bn0[2][2], bn1[2][2];

    auto stA = [&](int b, int h, int kt) {
#pragma unroll
        for (int i = h * 2; i < h * 2 + 2; ++i)
            __builtin_amdgcn_global_load_lds(
                (g_u8*)(Ap + (size_t)i * 64 * K + kt * 64),
                (lds_u8*)(lds + b * 32768 + i * 8192 + wid * 1024), 16, 0, 0);
    };
    auto stB = [&](int b, int h, int kt) {
#pragma unroll
        for (int i = h * 2; i < h * 2 + 2; ++i)
            __builtin_amdgcn_global_load_lds(
                (g_u8*)(Wp + (size_t)i * 64 * K + kt * 64),
                (lds_u8*)(lds + 65536 + b * 32768 + i * 8192 + wid * 1024), 16, 0, 0);
    };
    auto rdA = [&](int b, int mh) {
        int base = b * 32768 + (mh ? rbA1 : rbA0);
#pragma unroll
        for (int fm = 0; fm < 4; ++fm) {
            am[fm][0] = *(const bf16x8*)(lds + base + fm * 2048 + cb0);
            am[fm][1] = *(const bf16x8*)(lds + base + fm * 2048 + cb1);
        }
    };
    auto rdB = [&](int b, int nh, bf16x8 (&bn)[2][2]) {
        int base = 65536 + b * 32768 + (nh ? rbB1 : rbB0);
#pragma unroll
        for (int fn = 0; fn < 2; ++fn) {
            bn[fn][0] = *(const bf16x8*)(lds + base + fn * 2048 + cb0);
            bn[fn][1] = *(const bf16x8*)(lds + base + fn * 2048 + cb1);
        }
    };
    auto mq = [&](int mh, int nh, bf16x8 (&bn)[2][2]) {
        __builtin_amdgcn_s_setprio(1);
#pragma unroll
        for (int fm = 0; fm < 4; ++fm)
#pragma unroll
            for (int fn = 0; fn < 2; ++fn)
#pragma unroll
                for (int ks = 0; ks < 2; ++ks)
                    acc[mh * 4 + fm][nh * 2 + fn] =
                        __builtin_amdgcn_mfma_f32_16x16x32_bf16(
                            am[fm][ks], bn[fn][ks], acc[mh * 4 + fm][nh * 2 + fn], 0, 0, 0);
        __builtin_amdgcn_s_setprio(0);
    };

    stA(0, 0, 0); stA(0, 1, 0);
    stB(0, 0, 0); stB(0, 1, 0);
    stB(1, 0, 1); stB(1, 1, 1);
    VMCNT4;
    BARRIER;

    for (int it = 0; it < NT2; ++it) {
        const int k1 = 2 * it + 1;
        const int k2 = (2 * it + 2 < NT) ? 2 * it + 2 : NT - 1;
        const int k3 = (2 * it + 3 < NT) ? 2 * it + 3 : NT - 1;
        rdA(0, 0); rdB(0, 0, bn0);
        stA(1, 0, k1);
        LGKM0; BARRIER;
        mq(0, 0, bn0);
        rdB(0, 1, bn1);
        stA(1, 1, k1);
        LGKM0; BARRIER;
        mq(0, 1, bn1);
        rdA(0, 1);
        stB(0, 0, k2);
        LGKM0; BARRIER;
        mq(1, 1, bn1);
        stB(0, 1, k2);
        VMCNT4; BARRIER;
        mq(1, 0, bn0);
        rdA(1, 0); rdB(1, 0, bn0);
        stA(0, 0, k2);
        LGKM0; BARRIER;
        mq(0, 0, bn0);
        rdB(1, 1, bn1);
        stA(0, 1, k2);
        LGKM0; BARRIER;
        mq(0, 1, bn1);
        rdA(1, 1);
        stB(1, 0, k3);
        LGKM0; BARRIER;
        mq(1, 1, bn1);
        stB(1, 1, k3);
        VMCNT4; BARRIER;
        mq(1, 0, bn0);
    }

    if (MODE != 3) {
        // bf16 staging [256][264], fully-coalesced u16x8 writeback
        unsigned short* sb = (unsigned short*)lds;
#pragma unroll
        for (int j = 0; j < 4; ++j) {
            int colL = wc * 64 + j * 16 + llo;
            float bv = bias[n0 + colL];
#pragma unroll
            for (int i = 0; i < 8; ++i) {
                int rowL = wr * 128 + i * 16 + lhi * 4;
#pragma unroll
                for (int r = 0; r < 4; ++r) {
                    float o = acc[i][j][r] + bv;
                    if (MODE == 2) o = o / (1.0f + __expf(-1.702f * o));
                    sb[(rowL + r) * 264 + colL] = f2bf(o);
                }
            }
        }
        __syncthreads();
        const int l5 = lane & 31, lh2 = lane >> 5;
#pragma unroll
        for (int rr = 0; rr < 16; ++rr) {
            int rowL = rr * 16 + wid * 2 + lh2;
            u16x8 v = *(const u16x8*)&sb[rowL * 264 + l5 * 8];
            *(u16x8*)((unsigned short*)Cout + (size_t)(m0 + rowL) * N + n0 + l5 * 8) = v;
        }
    } else {
        // f32 staging [128][260]; residual added in f32; bf16 out (ushort4)
        float* sf = (float*)lds;
#pragma unroll
        for (int mh = 0; mh < 2; ++mh) {
            if (mh) __syncthreads();
            if (wr == mh) {
#pragma unroll
                for (int j = 0; j < 4; ++j) {
                    int colL = wc * 64 + j * 16 + llo;
                    float bv = bias[n0 + colL];
#pragma unroll
                    for (int i = 0; i < 8; ++i) {
                        int rowL = i * 16 + lhi * 4;
#pragma unroll
                        for (int r = 0; r < 4; ++r)
                            sf[(rowL + r) * 260 + colL] = acc[i][j][r] + bv;
                    }
                }
            }
            __syncthreads();
#pragma unroll
            for (int rr = 0; rr < 16; ++rr) {
                int rowL = rr * 8 + wid;
                size_t gidx = (size_t)(m0 + mh * 128 + rowL) * N + n0 + lane * 4;
                f32x4 v = *(const f32x4*)&sf[rowL * 260 + lane * 4];
                ushort4 rv = *(const ushort4*)&R[gidx];
                ushort4 o;
                o.x = f2bf(v[0] + bf2f(rv.x));
                o.y = f2bf(v[1] + bf2f(rv.y));
                o.z = f2bf(v[2] + bf2f(rv.z));
                o.w = f2bf(v[3] + bf2f(rv.w));
                *(ushort4*)((unsigned short*)Cout + gidx) = o;
            }
        }
    }
}

// ======================================================================
// MFMA attention: one block per (b,h), 4 waves, bf16 qkv input.
// 16-lane-group softmax, V reg-prefetch, P cols 77..95 exactly zero.
// ======================================================================
__global__ __launch_bounds__(256) void attn_mfma_kernel(
    const unsigned short* __restrict__ qkv, const int* __restrict__ amask,
    unsigned short* __restrict__ out)
{
    const int bh = blockIdx.x;
    const int b = bh >> 3;
    const int h = bh & 7;
    __shared__ __align__(16) char smem[68160];
    char* Qs = smem;
    char* Ks = smem + 10240;
    char* Vt = smem;
    char* Pb = smem + 20480;
    float* ss = (float*)(smem + 40960);
    float* padm = (float*)(smem + 67840);
    const int tid  = threadIdx.x;
    const int wid  = tid >> 6;
    const int lane = tid & 63;
    const int llo  = lane & 15;
    const int lhi  = lane >> 4;

    const size_t vbase = ((size_t)(b * SEQ)) * NQKV + 1024 + h * DHEAD;
    bf16x8 vr0, vr1, vr2;
    {
        int c0 = tid, c1 = tid + 256, c2 = tid + 512;
        vr0 = *(const bf16x8*)&qkv[vbase + (size_t)(c0 >> 3) * NQKV + (c0 & 7) * 8];
        vr1 = *(const bf16x8*)&qkv[vbase + (size_t)(c1 >> 3) * NQKV + (c1 & 7) * 8];
        if (c2 < 616)
            vr2 = *(const bf16x8*)&qkv[vbase + (size_t)(c2 >> 3) * NQKV + (c2 & 7) * 8];
    }

    if (tid < 160) {
        int r = tid >> 1, ch = 10 + (tid & 1);
        bf16x8 z;
#pragma unroll
        for (int j = 0; j < 8; ++j) z[j] = 0;
        *(bf16x8*)(Pb + r * 256 + ((ch ^ (r & 7)) * 16)) = z;
    }

    for (int f = tid; f < 640; f += 256) {
        int r = f >> 3, c = f & 7;
        bf16x8 pq, pk;
        if (r < SEQ) {
            size_t g = ((size_t)(b * SEQ + r)) * NQKV + h * DHEAD + c * 8;
            pq = *(const bf16x8*)&qkv[g];
            pk = *(const bf16x8*)&qkv[g + 512];
        } else {
#pragma unroll
            for (int j = 0; j < 8; ++j) { pq[j] = 0; pk[j] = 0; }
        }
        int byte = r * 128 + ((c * 16) ^ ((r & 7) << 4));
        *(bf16x8*)(Qs + byte) = pq;
        *(bf16x8*)(Ks + byte) = pk;
    }
    for (int s = tid; s < SEQ; s += 256)
        padm[s] = (1.0f - (float)amask[b * SEQ + s]) * NEGBIG;
    __syncthreads();

    for (int t = wid; t < 25; t += 4) {
        int rt = t / 5, ct = t % 5;
        int ar = rt * 16 + llo;
        int br = ct * 16 + llo;
        int aswz = (ar & 7) << 4;
        int bswz = (br & 7) << 4;
        bf16x8 a0 = *(const bf16x8*)(Qs + ar * 128 + ((lhi * 16) ^ aswz));
        bf16x8 a1 = *(const bf16x8*)(Qs + ar * 128 + (((lhi + 4) * 16) ^ aswz));
        bf16x8 b0 = *(const bf16x8*)(Ks + br * 128 + ((lhi * 16) ^ bswz));
        bf16x8 b1 = *(const bf16x8*)(Ks + br * 128 + (((lhi + 4) * 16) ^ bswz));
        f32x4 acc = (f32x4){0.f, 0.f, 0.f, 0.f};
        acc = __builtin_amdgcn_mfma_f32_16x16x32_bf16(a0, b0, acc, 0, 0, 0);
        acc = __builtin_amdgcn_mfma_f32_16x16x32_bf16(a1, b1, acc, 0, 0, 0);
        int ki = ct * 16 + llo;
#pragma unroll
        for (int r = 0; r < 4; ++r) {
            int qi = rt * 16 + lhi * 4 + r;
            ss[qi * 84 + ki] = (ki > qi || ki >= SEQ) ? NEGBIG : (acc[r] + padm[ki]);
        }
    }
    __syncthreads();

    {
        auto writeV = [&](int c, bf16x8 v) {
            int s = c >> 3, d8 = (c & 7) * 8;
            int chunk16 = (s >> 3) * 16, within = (s & 7) * 2;
#pragma unroll
            for (int j = 0; j < 8; ++j) {
                int d = d8 + j;
                *(short*)(Vt + d * 256 + (chunk16 ^ ((d & 7) << 4)) + within) = v[j];
            }
        };
        writeV(tid, vr0);
        writeV(tid + 256, vr1);
        if (tid + 512 < 616) writeV(tid + 512, vr2);
    }

    {
        const int g = lane >> 4;
        const int c = lane & 15;
#pragma unroll
        for (int pass = 0; pass < 5; ++pass) {
            int r = pass * 16 + wid * 4 + g;
            float v0 = ss[r * 84 + c];
            float v1 = ss[r * 84 + c + 16];
            float v2 = ss[r * 84 + c + 32];
            float v3 = ss[r * 84 + c + 48];
            float v4 = ss[r * 84 + c + 64];
            float m = fmaxf(fmaxf(fmaxf(v0, v1), fmaxf(v2, v3)), v4);
#pragma unroll
            for (int o = 8; o; o >>= 1) m = fmaxf(m, __shfl_xor(m, o));
            float e0 = __expf(v0 - m), e1 = __expf(v1 - m), e2 = __expf(v2 - m);
            float e3 = __expf(v3 - m), e4 = __expf(v4 - m);
            float tsum = e0 + e1 + e2 + e3 + e4;
#pragma unroll
            for (int o = 8; o; o >>= 1) tsum += __shfl_xor(tsum, o);
            float rinv = 1.0f / tsum;
            int rswz = (r & 7) << 4;
            int rb = r * 256;
            float ev[5] = {e0, e1, e2, e3, e4};
#pragma unroll
            for (int i = 0; i < 5; ++i) {
                int col = c + i * 16;
                *(short*)(Pb + rb + (((col >> 3) * 16) ^ rswz) + (col & 7) * 2) =
                    (short)f2bf(ev[i] * rinv);
            }
        }
    }
    __syncthreads();

    for (int t = wid; t < 20; t += 4) {
        int rt = t >> 2, ct = t & 3;
        int ar = rt * 16 + llo;
        int br = ct * 16 + llo;
        int aswz = (ar & 7) << 4;
        int bswz = (br & 7) << 4;
        f32x4 acc = (f32x4){0.f, 0.f, 0.f, 0.f};
#pragma unroll
        for (int kc = 0; kc < 3; ++kc) {
            bf16x8 af  = *(const bf16x8*)(Pb + ar * 256 + (((kc * 4 + lhi) * 16) ^ aswz));
            bf16x8 bf_ = *(const bf16x8*)(Vt + br * 256 + (((kc * 4 + lhi) * 16) ^ bswz));
            acc = __builtin_amdgcn_mfma_f32_16x16x32_bf16(af, bf_, acc, 0, 0, 0);
        }
        int d = ct * 16 + llo;
#pragma unroll
        for (int r = 0; r < 4; ++r) {
            int qi = rt * 16 + lhi * 4 + r;
            if (qi < SEQ)
                out[((size_t)(b * SEQ + qi)) * DMODEL + h * DHEAD + d] = f2bf(acc[r]);
        }
    }
}

// ======================================================================
// Pooled output (reads f32 last_hidden from d_out)
// ======================================================================
__global__ __launch_bounds__(64) void pool_kernel(
    const int* __restrict__ ids, const float* __restrict__ lh,
    float* __restrict__ pooled)
{
    int b = blockIdx.x;
    int ln = threadIdx.x;
    __shared__ int sidx;
    if (ln == 0) {
        int best = ids[b * SEQ]; int bi = 0;
        for (int s = 1; s < SEQ; ++s) {
            int vv = ids[b * SEQ + s];
            if (vv > best) { best = vv; bi = s; }
        }
        sidx = bi;
    }
    __syncthreads();
    const float* src = lh + ((size_t)(b * SEQ + sidx)) * DMODEL + ln * 8;
    float* dst = pooled + (size_t)b * DMODEL + ln * 8;
    float4 a = *(const float4*)src;
    float4 c = *(const float4*)(src + 4);
    *(float4*)dst       = a;
    *(float4*)(dst + 4) = c;
}

// ======================================================================
extern "C" void kernel_launch(void* const* d_in, const int* in_sizes, int n_in,
                              void* d_out, int out_size, void* d_ws, size_t ws_size,
                              hipStream_t stream) {
    const int*   ids   = (const int*)d_in[0];
    const int*   amask = (const int*)d_in[1];
    const float* tok   = (const float*)d_in[2];
    const float* pos   = (const float*)d_in[3];
    const float* ln1w  = (const float*)d_in[4];
    const float* ln1b  = (const float*)d_in[5];
    const float* qw    = (const float*)d_in[6];
    const float* qbias = (const float*)d_in[7];
    const float* kw    = (const float*)d_in[8];
    const float* kbias = (const float*)d_in[9];
    const float* vw    = (const float*)d_in[10];
    const float* vbias = (const float*)d_in[11];
    const float* ow    = (const float*)d_in[12];
    const float* obias = (const float*)d_in[13];
    const float* ln2w  = (const float*)d_in[14];
    const float* ln2b  = (const float*)d_in[15];
    const float* f1w   = (const float*)d_in[16];
    const float* f1b   = (const float*)d_in[17];
    const float* f2w   = (const float*)d_in[18];
    const float* f2b   = (const float*)d_in[19];
    const float* lnfw  = (const float*)d_in[20];
    const float* lnfb  = (const float*)d_in[21];

    char* p = (char*)d_ws;
    unsigned short* x = (unsigned short*)p;    p += (size_t)NTOK * DMODEL * 2;
    unsigned short* hbuf = (unsigned short*)p; p += (size_t)NTOK * DMODEL * 2;
    unsigned short* qkvb = (unsigned short*)p; p += (size_t)NTOK * NQKV * 2;
    unsigned short* ao = (unsigned short*)p;   p += (size_t)NTOK * DMODEL * 2;
    unsigned short* ff = (unsigned short*)p;   p += (size_t)NTOK * DFF * 2;
    unsigned short* wqkv = (unsigned short*)p; p += (size_t)NLAYER * NQKV * DMODEL * 2;
    unsigned short* wo   = (unsigned short*)p; p += (size_t)NLAYER * DMODEL * DMODEL * 2;
    unsigned short* wf1  = (unsigned short*)p; p += (size_t)NLAYER * DFF * DMODEL * 2;
    unsigned short* wf2  = (unsigned short*)p; p += (size_t)NLAYER * DMODEL * DFF * 2;
    float* bqkv = (float*)p;                   p += (size_t)NLAYER * NQKV * 4;

    conv_qkv_kernel<<<(NLAYER * NQKV * DMODEL / 4) / 256, 256, 0, stream>>>(qw, kw, vw, wqkv);
    conv_kernel<<<(NLAYER * DMODEL * DMODEL / 4) / 256, 256, 0, stream>>>(ow, wo);
    conv_kernel<<<(NLAYER * DFF * DMODEL / 4) / 256, 256, 0, stream>>>(f1w, wf1);
    conv_kernel<<<(NLAYER * DMODEL * DFF / 4) / 256, 256, 0, stream>>>(f2w, wf2);
    bias_qkv_kernel<<<(NLAYER * NQKV) / 256, 256, 0, stream>>>(qbias, kbias, vbias, bqkv);

    embed_kernel<<<(NTOK * (DMODEL / 4) + 255) / 256, 256, 0, stream>>>(ids, tok, pos, x);

    const int MB = NTOK / 256;            // 77
    dim3 gqkv(MB * (NQKV / 256));         // 462
    dim3 g512(MB * (DMODEL / 256));       // 154
    dim3 g2048(MB * (DFF / 256));         // 616

    for (int l = 0; l < NLAYER; ++l) {
        const size_t wD2 = (size_t)l * DMODEL * DMODEL;
        const size_t wDF = (size_t)l * DFF * DMODEL;
        const size_t oD  = (size_t)l * DMODEL;
        const size_t oF  = (size_t)l * DFF;

        ln_kernel<true><<<NTOK / 4, 256, 0, stream>>>(x, ln1w + oD, ln1b + oD, hbuf, NTOK);
        gemm8_bf16<0><<<gqkv, 512, 0, stream>>>(
            hbuf, wqkv + (size_t)l * NQKV * DMODEL, bqkv + (size_t)l * NQKV, nullptr,
            qkvb, NTOK, NQKV, DMODEL, NQKV / 256);
        attn_mfma_kernel<<<BATCH * NHEAD, 256, 0, stream>>>(qkvb, amask, ao);
        gemm8_bf16<3><<<g512, 512, 0, stream>>>(
            ao, wo + wD2, obias + oD, x, x, NTOK, DMODEL, DMODEL, DMODEL / 256);
        ln_kernel<true><<<NTOK / 4, 256, 0, stream>>>(x, ln2w + oD, ln2b + oD, hbuf, NTOK);
        gemm8_bf16<2><<<g2048, 512, 0, stream>>>(
            hbuf, wf1 + wDF, f1b + oF, nullptr, ff, NTOK, DFF, DMODEL, DFF / 256);
        gemm8_bf16<3><<<g512, 512, 0, stream>>>(
            ff, wf2 + wDF, f2b + oD, x, x, NTOK, DMODEL, DFF, DMODEL / 256);
    }

    float* outf = (float*)d_out;
    ln_kernel<false><<<NTOK / 4, 256, 0, stream>>>(x, lnfw, lnfb, outf, NTOK);
    pool_kernel<<<BATCH, 64, 0, stream>>>(ids, outf, outf + (size_t)NTOK * DMODEL);
}